// Round 20
// baseline (511.253 us; speedup 1.0000x reference)
//
#include <hip/hip_runtime.h>
#include <hip/hip_fp16.h>
#include <math.h>

#define N_NODES 50000
#define N_EDGES 800000
#define F_IN    128
#define HID     64
#define HEADS   4
#define HC      256      // HEADS*HID
#define HC2     512      // xl|xr concatenated row
#define EDIM    9
#define EDUP    10       // padded ea row: {e0..e8, 0} fp32 (40B, splat in-reg)
#define NSCAN   ((N_NODES + 255) / 256)   // 196

typedef float v2f __attribute__((ext_vector_type(2)));
typedef float f32x4 __attribute__((ext_vector_type(4)));
typedef _Float16 half8 __attribute__((ext_vector_type(8)));

__device__ inline v2f cvt2(unsigned int u) {
    const __half2 h = __builtin_bit_cast(__half2, u);
    const float2 f = __half22float2(h);
    return (v2f){f.x, f.y};
}

// DPP add: x += lane-permuted x, stays in the VALU pipe (no LDS round-trip).
template<int CTRL>
__device__ inline float dpp_add(float x) {
    const int p = __builtin_amdgcn_update_dpp(0, __builtin_bit_cast(int, x),
                                              CTRL, 0xF, 0xF, true);
    return x + __builtin_bit_cast(float, p);
}
// 16-lane sum, every lane gets the total (proven r12/r15/r17/r18):
__device__ inline float reduce16(float l) {
    l = dpp_add<0xB1>(l);     // quad_perm xor1
    l = dpp_add<0x4E>(l);     // quad_perm xor2
    l = dpp_add<0x124>(l);    // row_ror:4
    l = dpp_add<0x128>(l);    // row_ror:8
    return l;
}

// ---------------- fp32 -> fp16 convert for layer-0 x ----------------
__global__ void convert_x(const float* __restrict__ in, _Float16* __restrict__ out, int n8) {
    const int i = blockIdx.x * 256 + threadIdx.x;
    if (i >= n8) return;
    const float4 f0 = *(const float4*)(in + (size_t)i * 8);
    const float4 f1 = *(const float4*)(in + (size_t)i * 8 + 4);
    half8 o;
    o[0] = (_Float16)f0.x; o[1] = (_Float16)f0.y; o[2] = (_Float16)f0.z; o[3] = (_Float16)f0.w;
    o[4] = (_Float16)f1.x; o[5] = (_Float16)f1.y; o[6] = (_Float16)f1.z; o[7] = (_Float16)f1.w;
    *(half8*)(out + (size_t)i * 8) = o;
}

// ---- pack Wl|Wr into MFMA B-fragment layout (fp16) + biascat ----
template<int K>
__global__ void pack_w(const float* __restrict__ Wl, const float* __restrict__ Wr,
                       const float* __restrict__ bl, const float* __restrict__ br,
                       _Float16* __restrict__ Wp, float* __restrict__ biascat) {
    constexpr int KS = K / 32;
    const int tid = blockIdx.x * 256 + threadIdx.x;
    if (tid < HC2) biascat[tid] = (tid < HC) ? bl[tid] : br[tid - HC];
    if (tid >= 32 * KS * 64) return;
    const int l = tid & 63;
    const int rest = tid >> 6;
    const int ks = rest % KS;
    const int ct = rest / KS;
    const int col = ct * 16 + (l & 15);
    const int kb = ks * 32 + (l >> 4) * 8;
    half8 o;
    #pragma unroll
    for (int j = 0; j < 8; ++j) {
        const int k = kb + j;
        const float v = (col < HC) ? Wl[(size_t)k * HC + col] : Wr[(size_t)k * HC + col - HC];
        o[j] = (_Float16)v;
    }
    *(half8*)(Wp + (size_t)tid * 8) = o;
}

// ---------------- node transform via MFMA: 2 M-tiles (32 nodes) per wave ----------------
// Halves per-wave Wp L2 traffic vs 1-tile (B-fragment reused for both A-frags).
template<int K>
__global__ __launch_bounds__(256) void nt_mfma(
        const _Float16* __restrict__ xin, const _Float16* __restrict__ Wp,
        const float* __restrict__ biascat, __half* __restrict__ xlr) {
    constexpr int KS = K / 32;
    const int MT = N_NODES / 16;                       // 3125
    const int mt0 = (blockIdx.x * 4 + (threadIdx.x >> 6)) * 2;
    if (mt0 >= MT) return;
    const bool two = (mt0 + 1 < MT);
    const int lane = threadIdx.x & 63;
    const int l15 = lane & 15;
    const int kg = lane >> 4;

    half8 a0[KS], a1[KS];
    #pragma unroll
    for (int ks = 0; ks < KS; ++ks) {
        a0[ks] = *(const half8*)(xin + (size_t)(mt0 * 16 + l15) * K + ks * 32 + kg * 8);
        a1[ks] = two ? *(const half8*)(xin + (size_t)((mt0 + 1) * 16 + l15) * K + ks * 32 + kg * 8)
                     : a0[ks];
    }

    const half8* __restrict__ Wp8 = (const half8*)Wp;
    #pragma unroll 2
    for (int ct = 0; ct < 32; ++ct) {
        f32x4 d0 = {0.f, 0.f, 0.f, 0.f};
        f32x4 d1 = {0.f, 0.f, 0.f, 0.f};
        #pragma unroll
        for (int ks = 0; ks < KS; ++ks) {
            const half8 b = Wp8[(size_t)(ct * KS + ks) * 64 + lane];
            d0 = __builtin_amdgcn_mfma_f32_16x16x32_f16(a0[ks], b, d0, 0, 0, 0);
            d1 = __builtin_amdgcn_mfma_f32_16x16x32_f16(a1[ks], b, d1, 0, 0, 0);
        }
        const float bc = biascat[ct * 16 + l15];
        #pragma unroll
        for (int r = 0; r < 4; ++r) {
            const int node0 = mt0 * 16 + kg * 4 + r;
            xlr[(size_t)node0 * HC2 + ct * 16 + l15] = __float2half(d0[r] + bc);
            if (two)
                xlr[(size_t)(node0 + 16) * HC2 + ct * 16 + l15] = __float2half(d1[r] + bc);
        }
    }
}

// ---------------- CSR build (once per launch) ----------------
__global__ void zero_counts(int* __restrict__ counts, int* __restrict__ cursor) {
    const int i = blockIdx.x * blockDim.x + threadIdx.x;
    if (i < N_NODES) { counts[i] = 0; cursor[i] = 0; }
}

__global__ void count_deg(const int* __restrict__ dst, int* __restrict__ counts) {
    const int e = blockIdx.x * blockDim.x + threadIdx.x;
    if (e < N_EDGES) atomicAdd(&counts[dst[e]], 1);
}

__global__ void scanA(const int* __restrict__ counts, int* __restrict__ bsum) {
    __shared__ int s[256];
    const int t = threadIdx.x;
    const int i = blockIdx.x * 256 + t;
    s[t] = (i < N_NODES) ? counts[i] : 0;
    __syncthreads();
    for (int st = 128; st > 0; st >>= 1) {
        if (t < st) s[t] += s[t + st];
        __syncthreads();
    }
    if (t == 0) bsum[blockIdx.x] = s[0];
}

__global__ void scanB(const int* __restrict__ bsum, int* __restrict__ boff) {
    __shared__ int s[256];
    const int t = threadIdx.x;
    const int orig = (t < NSCAN) ? bsum[t] : 0;
    s[t] = orig;
    __syncthreads();
    for (int st = 1; st < 256; st <<= 1) {
        int v = (t >= st) ? s[t - st] : 0;
        __syncthreads();
        s[t] += v;
        __syncthreads();
    }
    if (t < NSCAN) boff[t] = s[t] - orig;   // exclusive
}

__global__ void scanC(const int* __restrict__ counts, const int* __restrict__ boff,
                      int* __restrict__ offs) {
    __shared__ int s[256];
    const int t = threadIdx.x;
    const int i = blockIdx.x * 256 + t;
    const int orig = (i < N_NODES) ? counts[i] : 0;
    s[t] = orig;
    __syncthreads();
    for (int st = 1; st < 256; st <<= 1) {
        int v = (t >= st) ? s[t - st] : 0;
        __syncthreads();
        s[t] += v;
        __syncthreads();
    }
    if (i < N_NODES) offs[i] = boff[blockIdx.x] + s[t] - orig;  // exclusive
    if (i == 0) offs[N_NODES] = N_EDGES;
}

// fill CSR + scatter-write compact 40B fp32 ea rows with NONTEMPORAL stores
// (lines are written once, read once next kernel — skip L2 retention/RMW cost).
// NOTE: nontemporal builtin needs clang ext_vector types, not HIP float4.
__global__ void fill_csr(const int* __restrict__ src, const int* __restrict__ dst,
                         const int* __restrict__ offs, int* __restrict__ cursor,
                         const float* __restrict__ ea,
                         int* __restrict__ srcp, float* __restrict__ eap) {
    const int e = blockIdx.x * blockDim.x + threadIdx.x;
    if (e >= N_EDGES) return;
    const int d = dst[e];
    const int pos = offs[d] + atomicAdd(&cursor[d], 1);
    __builtin_nontemporal_store(src[e], &srcp[pos]);
    float v[EDUP + 2];
    #pragma unroll
    for (int u = 0; u < EDIM; ++u) v[u] = ea[(size_t)e * EDIM + u];
    v[9] = 0.f;
    float* o = eap + (size_t)pos * EDUP;
    const f32x4 v0 = {v[0], v[1], v[2], v[3]};
    const f32x4 v1 = {v[4], v[5], v[6], v[7]};
    const v2f   v2 = {v[8], v[9]};
    __builtin_nontemporal_store(v0, (f32x4*)(o));
    __builtin_nontemporal_store(v1, (f32x4*)(o + 4));
    __builtin_nontemporal_store(v2, (v2f*)(o + 8));
}

// ---------------- fused per-dst-node edge kernel ----------------
// One wave per destination node (97us proven structure, unchanged from r18).
__global__ __launch_bounds__(64) void fused_edge(
        const __half* __restrict__ xlr,
        const float* __restrict__ eap,
        const int* __restrict__ offs, const int* __restrict__ srcp,
        const float* __restrict__ We, const float* __restrict__ att,
        const float* __restrict__ bias, const float* __restrict__ gates,
        float* __restrict__ h, __half* __restrict__ hact, int layer) {
    const int d = blockIdx.x;
    const int lane = threadIdx.x;
    const int c0 = lane * 4;

    v2f vxr01, vxr23;
    {
        const uint2 raw = *(const uint2*)(xlr + (size_t)d * HC2 + HC + c0);
        vxr01 = cvt2(raw.x); vxr23 = cvt2(raw.y);
    }
    const float4 wa4 = *(const float4*)(att + c0);
    const float wa0 = wa4.x * 1.44269504f, wa1 = wa4.y * 1.44269504f,
                wa2 = wa4.z * 1.44269504f, wa3 = wa4.w * 1.44269504f;
    v2f wWe01[EDIM], wWe23[EDIM];
    #pragma unroll
    for (int u = 0; u < EDIM; ++u) {
        const float4 w4 = *(const float4*)(We + u * HC + c0);
        wWe01[u] = (v2f){w4.x, w4.y};
        wWe23[u] = (v2f){w4.z, w4.w};
    }
    const v2f c02 = (v2f){0.2f, 0.2f};

    float den = 0.f;
    v2f acc01 = (v2f){0.f, 0.f}, acc23 = (v2f){0.f, 0.f};

    const int jb = offs[d], je = offs[d + 1];

    uint2 rawA, rawB;
    float eA[EDIM], eB[EDIM];

    auto loadE = [&](int j, uint2& raw, float (&ef)[EDIM]) {
        const int s = srcp[j];
        raw = *(const uint2*)(xlr + (size_t)s * HC2 + c0);
        const float* ep = eap + (size_t)j * EDUP;   // wave-uniform stream -> s_load
        #pragma unroll
        for (int u = 0; u < EDIM; ++u) ef[u] = ep[u];
    };

    auto compute = [&](const uint2 raw, const float (&ef)[EDIM]) {
        const v2f a01 = cvt2(raw.x), a23 = cvt2(raw.y);
        v2f m01 = a01 + vxr01;
        v2f m23 = a23 + vxr23;
        #pragma unroll
        for (int u = 0; u < EDIM; ++u) {
            const v2f ev = (v2f){ef[u], ef[u]};     // in-register splat (free)
            m01 = __builtin_elementwise_fma(ev, wWe01[u], m01);
            m23 = __builtin_elementwise_fma(ev, wWe23[u], m23);
        }
        const v2f s01 = __builtin_elementwise_max(m01, m01 * c02);
        const v2f s23 = __builtin_elementwise_max(m23, m23 * c02);
        float l = fmaf(s01.x, wa0, fmaf(s01.y, wa1, fmaf(s23.x, wa2, s23.y * wa3)));
        l = reduce16(l);                                  // DPP, VALU-pipe only
        const float p = __builtin_amdgcn_exp2f(fminf(l, 108.f));  // clamp never fires
        den += p;
        const v2f pp = (v2f){p, p};
        acc01 = __builtin_elementwise_fma(pp, a01, acc01);
        acc23 = __builtin_elementwise_fma(pp, a23, acc23);
    };

    int j = jb;
    if (j < je) loadE(j, rawA, eA);
    while (j + 1 < je) {
        loadE(j + 1, rawB, eB);
        compute(rawA, eA);
        if (j + 2 < je) {
            loadE(j + 2, rawA, eA);
            compute(rawB, eB);
        } else {
            compute(rawB, eB);
        }
        j += 2;
    }
    if (j < je) compute(rawA, eA);

    const float inv = 1.f / (den + 1e-16f);
    float4 v;
    v.x = acc01.x * inv; v.y = acc01.y * inv; v.z = acc23.x * inv; v.w = acc23.y * inv;
    v.x += __shfl_xor(v.x, 16, 64);  v.x += __shfl_xor(v.x, 32, 64);
    v.y += __shfl_xor(v.y, 16, 64);  v.y += __shfl_xor(v.y, 32, 64);
    v.z += __shfl_xor(v.z, 16, 64);  v.z += __shfl_xor(v.z, 32, 64);
    v.w += __shfl_xor(v.w, 16, 64);  v.w += __shfl_xor(v.w, 32, 64);

    if (lane < 16) {
        const int c = lane * 4;
        float4 outv;
        outv.x = fmaf(0.25f, v.x, bias[c + 0]);
        outv.y = fmaf(0.25f, v.y, bias[c + 1]);
        outv.z = fmaf(0.25f, v.z, bias[c + 2]);
        outv.w = fmaf(0.25f, v.w, bias[c + 3]);
        if (layer > 0) {
            const float g = 1.f / (1.f + __expf(-gates[layer - 1]));
            float4 pv = *(const float4*)(h + (size_t)d * HID + c);
            pv.x = fmaxf(pv.x, 0.01f * pv.x);
            pv.y = fmaxf(pv.y, 0.01f * pv.y);
            pv.z = fmaxf(pv.z, 0.01f * pv.z);
            pv.w = fmaxf(pv.w, 0.01f * pv.w);
            outv.x = g * outv.x + (1.f - g) * pv.x;
            outv.y = g * outv.y + (1.f - g) * pv.y;
            outv.z = g * outv.z + (1.f - g) * pv.z;
            outv.w = g * outv.w + (1.f - g) * pv.w;
        }
        *(float4*)(h + (size_t)d * HID + c) = outv;
        if (layer < 2) {   // pre-activated fp16 copy for next layer's nt_mfma
            const __half2 p01 = __floats2half2_rn(fmaxf(outv.x, 0.01f * outv.x),
                                                  fmaxf(outv.y, 0.01f * outv.y));
            const __half2 p23 = __floats2half2_rn(fmaxf(outv.z, 0.01f * outv.z),
                                                  fmaxf(outv.w, 0.01f * outv.w));
            uint2 o;
            o.x = __builtin_bit_cast(unsigned int, p01);
            o.y = __builtin_bit_cast(unsigned int, p23);
            *(uint2*)(hact + (size_t)d * HID + c) = o;
        }
    }
}

extern "C" void kernel_launch(void* const* d_in, const int* in_sizes, int n_in,
                              void* d_out, int out_size, void* d_ws, size_t ws_size,
                              hipStream_t stream) {
    const float* x     = (const float*)d_in[0];
    const float* ea    = (const float*)d_in[1];
    const float* iWl   = (const float*)d_in[2];
    const float* ibl   = (const float*)d_in[3];
    const float* iWr   = (const float*)d_in[4];
    const float* ibr   = (const float*)d_in[5];
    const float* iWe   = (const float*)d_in[6];
    const float* iatt  = (const float*)d_in[7];
    const float* ibias = (const float*)d_in[8];
    const float* Wl    = (const float*)d_in[9];
    const float* bl    = (const float*)d_in[10];
    const float* Wr    = (const float*)d_in[11];
    const float* br    = (const float*)d_in[12];
    const float* We    = (const float*)d_in[13];
    const float* att   = (const float*)d_in[14];
    const float* bias  = (const float*)d_in[15];
    const float* gates = (const float*)d_in[16];
    const int*   ei    = (const int*)d_in[17];
    const int* src = ei;
    const int* dst = ei + N_EDGES;

    __half*    xlr     = (__half*)d_ws;                       // 50000*512 half
    __half*    hact    = xlr + (size_t)N_NODES * HC2;         // 50000*64 half
    _Float16*  x16     = (_Float16*)(hact + (size_t)N_NODES * HID);  // 50000*128
    _Float16*  Wp      = x16 + (size_t)N_NODES * F_IN;        // 512*128
    float*     biascat = (float*)(Wp + 512 * 128);            // 512
    int* counts = (int*)(biascat + HC2);                      // 50000
    int* cursor = counts + N_NODES;                           // 50000
    int* offs   = cursor + N_NODES;                           // 50001
    int* bsum   = offs + N_NODES + 1;                         // 256
    int* boff   = bsum + 256;                                 // 256
    int* srcp   = boff + 256;                                 // 800000
    float* eap  = (float*)(((uintptr_t)(srcp + N_EDGES) + 15) & ~(uintptr_t)15);  // 32MB
    float* h    = (float*)d_out;

    zero_counts<<<(N_NODES + 255) / 256, 256, 0, stream>>>(counts, cursor);
    count_deg<<<(N_EDGES + 255) / 256, 256, 0, stream>>>(dst, counts);
    scanA<<<NSCAN, 256, 0, stream>>>(counts, bsum);
    scanB<<<1, 256, 0, stream>>>(bsum, boff);
    scanC<<<NSCAN, 256, 0, stream>>>(counts, boff, offs);
    fill_csr<<<(N_EDGES + 255) / 256, 256, 0, stream>>>(src, dst, offs, cursor, ea, srcp, eap);
    convert_x<<<(N_NODES * F_IN / 8 + 255) / 256, 256, 0, stream>>>(x, x16, N_NODES * F_IN / 8);

    const int MT = N_NODES / 16;                 // 3125 M-tiles
    const int NTB = ((MT + 1) / 2 + 3) / 4;      // 2 tiles/wave, 4 waves/block

    for (int layer = 0; layer < 3; ++layer) {
        const float* wl_   = (layer == 0) ? iWl   : Wl   + (size_t)(layer - 1) * HID * HC;
        const float* bl_   = (layer == 0) ? ibl   : bl   + (size_t)(layer - 1) * HC;
        const float* wr_   = (layer == 0) ? iWr   : Wr   + (size_t)(layer - 1) * HID * HC;
        const float* br_   = (layer == 0) ? ibr   : br   + (size_t)(layer - 1) * HC;
        const float* we_   = (layer == 0) ? iWe   : We   + (size_t)(layer - 1) * EDIM * HC;
        const float* att_  = (layer == 0) ? iatt  : att  + (size_t)(layer - 1) * HC;
        const float* bias_ = (layer == 0) ? ibias : bias + (size_t)(layer - 1) * HID;

        if (layer == 0) {
            pack_w<F_IN><<<32, 256, 0, stream>>>(wl_, wr_, bl_, br_, Wp, biascat);
            nt_mfma<F_IN><<<NTB, 256, 0, stream>>>(x16, Wp, biascat, xlr);
        } else {
            pack_w<HID><<<16, 256, 0, stream>>>(wl_, wr_, bl_, br_, Wp, biascat);
            nt_mfma<HID><<<NTB, 256, 0, stream>>>((const _Float16*)hact, Wp, biascat, xlr);
        }

        fused_edge<<<N_NODES, 64, 0, stream>>>(xlr, eap, offs, srcp,
                                               we_, att_, bias_, gates, h, hact, layer);
    }
}

// Round 21
// 433.619 us; speedup vs baseline: 1.1790x; 1.1790x over previous
//
#include <hip/hip_runtime.h>
#include <hip/hip_fp16.h>
#include <math.h>

#define N_NODES 50000
#define N_EDGES 800000
#define F_IN    128
#define HID     64
#define HEADS   4
#define HC      256      // HEADS*HID
#define HC2     512      // xl|xr concatenated row
#define EDIM    9
#define EDUP    10       // padded ea row: {e0..e8, 0} fp32 (40B, splat in-reg)
#define NSCAN   ((N_NODES + 255) / 256)   // 196

typedef float v2f __attribute__((ext_vector_type(2)));
typedef float f32x4 __attribute__((ext_vector_type(4)));
typedef _Float16 half8 __attribute__((ext_vector_type(8)));

__device__ inline v2f cvt2(unsigned int u) {
    const __half2 h = __builtin_bit_cast(__half2, u);
    const float2 f = __half22float2(h);
    return (v2f){f.x, f.y};
}

// DPP add: x += lane-permuted x, stays in the VALU pipe (no LDS round-trip).
template<int CTRL>
__device__ inline float dpp_add(float x) {
    const int p = __builtin_amdgcn_update_dpp(0, __builtin_bit_cast(int, x),
                                              CTRL, 0xF, 0xF, true);
    return x + __builtin_bit_cast(float, p);
}
// 16-lane sum, every lane gets the total (proven r12/r15/r17/r18):
__device__ inline float reduce16(float l) {
    l = dpp_add<0xB1>(l);     // quad_perm xor1
    l = dpp_add<0x4E>(l);     // quad_perm xor2
    l = dpp_add<0x124>(l);    // row_ror:4
    l = dpp_add<0x128>(l);    // row_ror:8
    return l;
}

// ---------------- fp32 -> fp16 convert for layer-0 x ----------------
__global__ void convert_x(const float* __restrict__ in, _Float16* __restrict__ out, int n8) {
    const int i = blockIdx.x * 256 + threadIdx.x;
    if (i >= n8) return;
    const float4 f0 = *(const float4*)(in + (size_t)i * 8);
    const float4 f1 = *(const float4*)(in + (size_t)i * 8 + 4);
    half8 o;
    o[0] = (_Float16)f0.x; o[1] = (_Float16)f0.y; o[2] = (_Float16)f0.z; o[3] = (_Float16)f0.w;
    o[4] = (_Float16)f1.x; o[5] = (_Float16)f1.y; o[6] = (_Float16)f1.z; o[7] = (_Float16)f1.w;
    *(half8*)(out + (size_t)i * 8) = o;
}

// ---- pack Wl|Wr into MFMA B-fragment layout (fp16) + biascat ----
template<int K>
__global__ void pack_w(const float* __restrict__ Wl, const float* __restrict__ Wr,
                       const float* __restrict__ bl, const float* __restrict__ br,
                       _Float16* __restrict__ Wp, float* __restrict__ biascat) {
    constexpr int KS = K / 32;
    const int tid = blockIdx.x * 256 + threadIdx.x;
    if (tid < HC2) biascat[tid] = (tid < HC) ? bl[tid] : br[tid - HC];
    if (tid >= 32 * KS * 64) return;
    const int l = tid & 63;
    const int rest = tid >> 6;
    const int ks = rest % KS;
    const int ct = rest / KS;
    const int col = ct * 16 + (l & 15);
    const int kb = ks * 32 + (l >> 4) * 8;
    half8 o;
    #pragma unroll
    for (int j = 0; j < 8; ++j) {
        const int k = kb + j;
        const float v = (col < HC) ? Wl[(size_t)k * HC + col] : Wr[(size_t)k * HC + col - HC];
        o[j] = (_Float16)v;
    }
    *(half8*)(Wp + (size_t)tid * 8) = o;
}

// ---------------- node transform via MFMA: 2 M-tiles (32 nodes) per wave ----------------
// Halves per-wave Wp L2 traffic vs 1-tile (B-fragment reused for both A-frags).
template<int K>
__global__ __launch_bounds__(256) void nt_mfma(
        const _Float16* __restrict__ xin, const _Float16* __restrict__ Wp,
        const float* __restrict__ biascat, __half* __restrict__ xlr) {
    constexpr int KS = K / 32;
    const int MT = N_NODES / 16;                       // 3125
    const int mt0 = (blockIdx.x * 4 + (threadIdx.x >> 6)) * 2;
    if (mt0 >= MT) return;
    const bool two = (mt0 + 1 < MT);
    const int lane = threadIdx.x & 63;
    const int l15 = lane & 15;
    const int kg = lane >> 4;

    half8 a0[KS], a1[KS];
    #pragma unroll
    for (int ks = 0; ks < KS; ++ks) {
        a0[ks] = *(const half8*)(xin + (size_t)(mt0 * 16 + l15) * K + ks * 32 + kg * 8);
        a1[ks] = two ? *(const half8*)(xin + (size_t)((mt0 + 1) * 16 + l15) * K + ks * 32 + kg * 8)
                     : a0[ks];
    }

    const half8* __restrict__ Wp8 = (const half8*)Wp;
    #pragma unroll 2
    for (int ct = 0; ct < 32; ++ct) {
        f32x4 d0 = {0.f, 0.f, 0.f, 0.f};
        f32x4 d1 = {0.f, 0.f, 0.f, 0.f};
        #pragma unroll
        for (int ks = 0; ks < KS; ++ks) {
            const half8 b = Wp8[(size_t)(ct * KS + ks) * 64 + lane];
            d0 = __builtin_amdgcn_mfma_f32_16x16x32_f16(a0[ks], b, d0, 0, 0, 0);
            d1 = __builtin_amdgcn_mfma_f32_16x16x32_f16(a1[ks], b, d1, 0, 0, 0);
        }
        const float bc = biascat[ct * 16 + l15];
        #pragma unroll
        for (int r = 0; r < 4; ++r) {
            const int node0 = mt0 * 16 + kg * 4 + r;
            xlr[(size_t)node0 * HC2 + ct * 16 + l15] = __float2half(d0[r] + bc);
            if (two)
                xlr[(size_t)(node0 + 16) * HC2 + ct * 16 + l15] = __float2half(d1[r] + bc);
        }
    }
}

// ---------------- CSR build (once per launch) ----------------
__global__ void zero_counts(int* __restrict__ counts, int* __restrict__ cursor) {
    const int i = blockIdx.x * blockDim.x + threadIdx.x;
    if (i < N_NODES) { counts[i] = 0; cursor[i] = 0; }
}

__global__ void count_deg(const int* __restrict__ dst, int* __restrict__ counts) {
    const int e = blockIdx.x * blockDim.x + threadIdx.x;
    if (e < N_EDGES) atomicAdd(&counts[dst[e]], 1);
}

__global__ void scanA(const int* __restrict__ counts, int* __restrict__ bsum) {
    __shared__ int s[256];
    const int t = threadIdx.x;
    const int i = blockIdx.x * 256 + t;
    s[t] = (i < N_NODES) ? counts[i] : 0;
    __syncthreads();
    for (int st = 128; st > 0; st >>= 1) {
        if (t < st) s[t] += s[t + st];
        __syncthreads();
    }
    if (t == 0) bsum[blockIdx.x] = s[0];
}

__global__ void scanB(const int* __restrict__ bsum, int* __restrict__ boff) {
    __shared__ int s[256];
    const int t = threadIdx.x;
    const int orig = (t < NSCAN) ? bsum[t] : 0;
    s[t] = orig;
    __syncthreads();
    for (int st = 1; st < 256; st <<= 1) {
        int v = (t >= st) ? s[t - st] : 0;
        __syncthreads();
        s[t] += v;
        __syncthreads();
    }
    if (t < NSCAN) boff[t] = s[t] - orig;   // exclusive
}

__global__ void scanC(const int* __restrict__ counts, const int* __restrict__ boff,
                      int* __restrict__ offs) {
    __shared__ int s[256];
    const int t = threadIdx.x;
    const int i = blockIdx.x * 256 + t;
    const int orig = (i < N_NODES) ? counts[i] : 0;
    s[t] = orig;
    __syncthreads();
    for (int st = 1; st < 256; st <<= 1) {
        int v = (t >= st) ? s[t - st] : 0;
        __syncthreads();
        s[t] += v;
        __syncthreads();
    }
    if (i < N_NODES) offs[i] = boff[blockIdx.x] + s[t] - orig;  // exclusive
    if (i == 0) offs[N_NODES] = N_EDGES;
}

// fill CSR + scatter-write compact 40B fp32 ea rows (PLAIN stores — r20 proved
// nontemporal bypassing L2 write-coalescing costs ~2x on scattered partial lines).
__global__ void fill_csr(const int* __restrict__ src, const int* __restrict__ dst,
                         const int* __restrict__ offs, int* __restrict__ cursor,
                         const float* __restrict__ ea,
                         int* __restrict__ srcp, float* __restrict__ eap) {
    const int e = blockIdx.x * blockDim.x + threadIdx.x;
    if (e >= N_EDGES) return;
    const int d = dst[e];
    const int pos = offs[d] + atomicAdd(&cursor[d], 1);
    srcp[pos] = src[e];
    float v[EDUP + 2];
    #pragma unroll
    for (int u = 0; u < EDIM; ++u) v[u] = ea[(size_t)e * EDIM + u];
    v[9] = 0.f;
    float* o = eap + (size_t)pos * EDUP;
    *(float4*)(o)     = *(float4*)(v);
    *(float4*)(o + 4) = *(float4*)(v + 4);
    *(float2*)(o + 8) = *(float2*)(v + 8);
}

// ---------------- fused per-dst-node edge kernel ----------------
// One wave per destination node (97us proven structure, unchanged from r18).
__global__ __launch_bounds__(64) void fused_edge(
        const __half* __restrict__ xlr,
        const float* __restrict__ eap,
        const int* __restrict__ offs, const int* __restrict__ srcp,
        const float* __restrict__ We, const float* __restrict__ att,
        const float* __restrict__ bias, const float* __restrict__ gates,
        float* __restrict__ h, __half* __restrict__ hact, int layer) {
    const int d = blockIdx.x;
    const int lane = threadIdx.x;
    const int c0 = lane * 4;

    v2f vxr01, vxr23;
    {
        const uint2 raw = *(const uint2*)(xlr + (size_t)d * HC2 + HC + c0);
        vxr01 = cvt2(raw.x); vxr23 = cvt2(raw.y);
    }
    const float4 wa4 = *(const float4*)(att + c0);
    const float wa0 = wa4.x * 1.44269504f, wa1 = wa4.y * 1.44269504f,
                wa2 = wa4.z * 1.44269504f, wa3 = wa4.w * 1.44269504f;
    v2f wWe01[EDIM], wWe23[EDIM];
    #pragma unroll
    for (int u = 0; u < EDIM; ++u) {
        const float4 w4 = *(const float4*)(We + u * HC + c0);
        wWe01[u] = (v2f){w4.x, w4.y};
        wWe23[u] = (v2f){w4.z, w4.w};
    }
    const v2f c02 = (v2f){0.2f, 0.2f};

    float den = 0.f;
    v2f acc01 = (v2f){0.f, 0.f}, acc23 = (v2f){0.f, 0.f};

    const int jb = offs[d], je = offs[d + 1];

    uint2 rawA, rawB;
    float eA[EDIM], eB[EDIM];

    auto loadE = [&](int j, uint2& raw, float (&ef)[EDIM]) {
        const int s = srcp[j];
        raw = *(const uint2*)(xlr + (size_t)s * HC2 + c0);
        const float* ep = eap + (size_t)j * EDUP;   // wave-uniform stream -> s_load
        #pragma unroll
        for (int u = 0; u < EDIM; ++u) ef[u] = ep[u];
    };

    auto compute = [&](const uint2 raw, const float (&ef)[EDIM]) {
        const v2f a01 = cvt2(raw.x), a23 = cvt2(raw.y);
        v2f m01 = a01 + vxr01;
        v2f m23 = a23 + vxr23;
        #pragma unroll
        for (int u = 0; u < EDIM; ++u) {
            const v2f ev = (v2f){ef[u], ef[u]};     // in-register splat (free)
            m01 = __builtin_elementwise_fma(ev, wWe01[u], m01);
            m23 = __builtin_elementwise_fma(ev, wWe23[u], m23);
        }
        const v2f s01 = __builtin_elementwise_max(m01, m01 * c02);
        const v2f s23 = __builtin_elementwise_max(m23, m23 * c02);
        float l = fmaf(s01.x, wa0, fmaf(s01.y, wa1, fmaf(s23.x, wa2, s23.y * wa3)));
        l = reduce16(l);                                  // DPP, VALU-pipe only
        const float p = __builtin_amdgcn_exp2f(fminf(l, 108.f));  // clamp never fires
        den += p;
        const v2f pp = (v2f){p, p};
        acc01 = __builtin_elementwise_fma(pp, a01, acc01);
        acc23 = __builtin_elementwise_fma(pp, a23, acc23);
    };

    int j = jb;
    if (j < je) loadE(j, rawA, eA);
    while (j + 1 < je) {
        loadE(j + 1, rawB, eB);
        compute(rawA, eA);
        if (j + 2 < je) {
            loadE(j + 2, rawA, eA);
            compute(rawB, eB);
        } else {
            compute(rawB, eB);
        }
        j += 2;
    }
    if (j < je) compute(rawA, eA);

    const float inv = 1.f / (den + 1e-16f);
    float4 v;
    v.x = acc01.x * inv; v.y = acc01.y * inv; v.z = acc23.x * inv; v.w = acc23.y * inv;
    v.x += __shfl_xor(v.x, 16, 64);  v.x += __shfl_xor(v.x, 32, 64);
    v.y += __shfl_xor(v.y, 16, 64);  v.y += __shfl_xor(v.y, 32, 64);
    v.z += __shfl_xor(v.z, 16, 64);  v.z += __shfl_xor(v.z, 32, 64);
    v.w += __shfl_xor(v.w, 16, 64);  v.w += __shfl_xor(v.w, 32, 64);

    if (lane < 16) {
        const int c = lane * 4;
        float4 outv;
        outv.x = fmaf(0.25f, v.x, bias[c + 0]);
        outv.y = fmaf(0.25f, v.y, bias[c + 1]);
        outv.z = fmaf(0.25f, v.z, bias[c + 2]);
        outv.w = fmaf(0.25f, v.w, bias[c + 3]);
        if (layer > 0) {
            const float g = 1.f / (1.f + __expf(-gates[layer - 1]));
            float4 pv = *(const float4*)(h + (size_t)d * HID + c);
            pv.x = fmaxf(pv.x, 0.01f * pv.x);
            pv.y = fmaxf(pv.y, 0.01f * pv.y);
            pv.z = fmaxf(pv.z, 0.01f * pv.z);
            pv.w = fmaxf(pv.w, 0.01f * pv.w);
            outv.x = g * outv.x + (1.f - g) * pv.x;
            outv.y = g * outv.y + (1.f - g) * pv.y;
            outv.z = g * outv.z + (1.f - g) * pv.z;
            outv.w = g * outv.w + (1.f - g) * pv.w;
        }
        *(float4*)(h + (size_t)d * HID + c) = outv;
        if (layer < 2) {   // pre-activated fp16 copy for next layer's nt_mfma
            const __half2 p01 = __floats2half2_rn(fmaxf(outv.x, 0.01f * outv.x),
                                                  fmaxf(outv.y, 0.01f * outv.y));
            const __half2 p23 = __floats2half2_rn(fmaxf(outv.z, 0.01f * outv.z),
                                                  fmaxf(outv.w, 0.01f * outv.w));
            uint2 o;
            o.x = __builtin_bit_cast(unsigned int, p01);
            o.y = __builtin_bit_cast(unsigned int, p23);
            *(uint2*)(hact + (size_t)d * HID + c) = o;
        }
    }
}

extern "C" void kernel_launch(void* const* d_in, const int* in_sizes, int n_in,
                              void* d_out, int out_size, void* d_ws, size_t ws_size,
                              hipStream_t stream) {
    const float* x     = (const float*)d_in[0];
    const float* ea    = (const float*)d_in[1];
    const float* iWl   = (const float*)d_in[2];
    const float* ibl   = (const float*)d_in[3];
    const float* iWr   = (const float*)d_in[4];
    const float* ibr   = (const float*)d_in[5];
    const float* iWe   = (const float*)d_in[6];
    const float* iatt  = (const float*)d_in[7];
    const float* ibias = (const float*)d_in[8];
    const float* Wl    = (const float*)d_in[9];
    const float* bl    = (const float*)d_in[10];
    const float* Wr    = (const float*)d_in[11];
    const float* br    = (const float*)d_in[12];
    const float* We    = (const float*)d_in[13];
    const float* att   = (const float*)d_in[14];
    const float* bias  = (const float*)d_in[15];
    const float* gates = (const float*)d_in[16];
    const int*   ei    = (const int*)d_in[17];
    const int* src = ei;
    const int* dst = ei + N_EDGES;

    __half*    xlr     = (__half*)d_ws;                       // 50000*512 half
    __half*    hact    = xlr + (size_t)N_NODES * HC2;         // 50000*64 half
    _Float16*  x16     = (_Float16*)(hact + (size_t)N_NODES * HID);  // 50000*128
    _Float16*  Wp      = x16 + (size_t)N_NODES * F_IN;        // 512*128
    float*     biascat = (float*)(Wp + 512 * 128);            // 512
    int* counts = (int*)(biascat + HC2);                      // 50000
    int* cursor = counts + N_NODES;                           // 50000
    int* offs   = cursor + N_NODES;                           // 50001
    int* bsum   = offs + N_NODES + 1;                         // 256
    int* boff   = bsum + 256;                                 // 256
    int* srcp   = boff + 256;                                 // 800000
    float* eap  = (float*)(((uintptr_t)(srcp + N_EDGES) + 15) & ~(uintptr_t)15);  // 32MB
    float* h    = (float*)d_out;

    zero_counts<<<(N_NODES + 255) / 256, 256, 0, stream>>>(counts, cursor);
    count_deg<<<(N_EDGES + 255) / 256, 256, 0, stream>>>(dst, counts);
    scanA<<<NSCAN, 256, 0, stream>>>(counts, bsum);
    scanB<<<1, 256, 0, stream>>>(bsum, boff);
    scanC<<<NSCAN, 256, 0, stream>>>(counts, boff, offs);
    fill_csr<<<(N_EDGES + 255) / 256, 256, 0, stream>>>(src, dst, offs, cursor, ea, srcp, eap);
    convert_x<<<(N_NODES * F_IN / 8 + 255) / 256, 256, 0, stream>>>(x, x16, N_NODES * F_IN / 8);

    const int MT = N_NODES / 16;                 // 3125 M-tiles
    const int NTB = ((MT + 1) / 2 + 3) / 4;      // 2 tiles/wave, 4 waves/block

    for (int layer = 0; layer < 3; ++layer) {
        const float* wl_   = (layer == 0) ? iWl   : Wl   + (size_t)(layer - 1) * HID * HC;
        const float* bl_   = (layer == 0) ? ibl   : bl   + (size_t)(layer - 1) * HC;
        const float* wr_   = (layer == 0) ? iWr   : Wr   + (size_t)(layer - 1) * HID * HC;
        const float* br_   = (layer == 0) ? ibr   : br   + (size_t)(layer - 1) * HC;
        const float* we_   = (layer == 0) ? iWe   : We   + (size_t)(layer - 1) * EDIM * HC;
        const float* att_  = (layer == 0) ? iatt  : att  + (size_t)(layer - 1) * HC;
        const float* bias_ = (layer == 0) ? ibias : bias + (size_t)(layer - 1) * HID;

        if (layer == 0) {
            pack_w<F_IN><<<32, 256, 0, stream>>>(wl_, wr_, bl_, br_, Wp, biascat);
            nt_mfma<F_IN><<<NTB, 256, 0, stream>>>(x16, Wp, biascat, xlr);
        } else {
            pack_w<HID><<<16, 256, 0, stream>>>(wl_, wr_, bl_, br_, Wp, biascat);
            nt_mfma<HID><<<NTB, 256, 0, stream>>>((const _Float16*)hact, Wp, biascat, xlr);
        }

        fused_edge<<<N_NODES, 64, 0, stream>>>(xlr, eap, offs, srcp,
                                               we_, att_, bias_, gates, h, hact, layer);
    }
}